// Round 9
// baseline (345.739 us; speedup 1.0000x reference)
//
#include <hip/hip_runtime.h>
#include <math.h>

#define N_NODES 50000
#define N_EDGES 800000
#define IN_DIM 128
#define HIDDEN 128
#define CLASSES 64
#define N2 100000      // concatenated node space: graph1 [0,50000), graph2 [50000,100000)

#define BIN_SHIFT 8    // 256 nodes per bin
#define BIN_SZ 256
#define NB 391         // ceil(100000/256)
#define NBLK 256       // edge-partition blocks for P1/P2
#define CHUNK ((2 * N_EDGES + NBLK - 1) / NBLK)

static __device__ __forceinline__ float elu_f(float x) {
    return x > 0.f ? x : (expf(x) - 1.f);
}

static __device__ __forceinline__ void fma4(float4& a, const float4 w, const float s) {
    a.x = fmaf(w.x, s, a.x);
    a.y = fmaf(w.y, s, a.y);
    a.z = fmaf(w.z, s, a.z);
    a.w = fmaf(w.w, s, a.w);
}

// f32 -> bf16 (RNE) pack of two values into one uint (lo = first)
static __device__ __forceinline__ unsigned pack_bf2(float a, float b) {
    unsigned ua = __float_as_uint(a);
    ua = (ua + 0x7FFFu + ((ua >> 16) & 1u)) >> 16;
    unsigned ub = __float_as_uint(b);
    ub = (ub + 0x7FFFu + ((ub >> 16) & 1u)) >> 16;
    return ua | (ub << 16);
}

// unpack two bf16 (packed in uint) -> float2
static __device__ __forceinline__ float2 bf2f2(unsigned u) {
    float2 r;
    r.x = __uint_as_float(u << 16);
    r.y = __uint_as_float(u & 0xFFFF0000u);
    return r;
}

// accumulate 4 bf16 dims (uint2) into float4
static __device__ __forceinline__ void acc4(float4& a, const uint2 u) {
    const float2 lo = bf2f2(u.x);
    const float2 hi = bf2f2(u.y);
    a.x += lo.x; a.y += lo.y; a.z += hi.x; a.w += hi.y;
}

// ---------------------------------------------------------------------------
// P1: per-block LDS histogram over bins. counts[bin*NBLK + blk] (bin-major).
// ---------------------------------------------------------------------------
__global__ __launch_bounds__(1024) void k_p1_count(
    const int* __restrict__ dst1, const int* __restrict__ dst2,
    int* __restrict__ counts)
{
    __shared__ int hist[NB];
    const int t = threadIdx.x, b = blockIdx.x;
    if (t < NB) hist[t] = 0;
    __syncthreads();
    const int beg = b * CHUNK;
    const int end = min(beg + CHUNK, 2 * N_EDGES);
    for (int i = beg + t; i < end; i += 1024) {
        const int idx = (i < N_EDGES) ? dst1[i] : (N_NODES + dst2[i - N_EDGES]);
        atomicAdd(&hist[idx >> BIN_SHIFT], 1);
    }
    __syncthreads();
    if (t < NB) counts[t * NBLK + b] = hist[t];
}

// ---------------------------------------------------------------------------
// Scan: bin totals, exclusive scan over bins, in-place rewrite counts ->
// per-(bin,blk) start cursors. One 512-thread block.
// ---------------------------------------------------------------------------
__global__ __launch_bounds__(512) void k_scan_bins(
    int* __restrict__ counts, int* __restrict__ binStart, int* __restrict__ off)
{
    __shared__ int tot[512];
    const int t = threadIdx.x;
    int total = 0;
    if (t < NB) {
        const int4* p = reinterpret_cast<const int4*>(counts + t * NBLK);
        #pragma unroll 8
        for (int i = 0; i < NBLK / 4; ++i) {
            const int4 c = p[i];
            total += (c.x + c.y) + (c.z + c.w);
        }
    }
    tot[t] = (t < NB) ? total : 0;
    __syncthreads();
    const int v = tot[t];
    for (int d = 1; d < 512; d <<= 1) {
        const int x = (t >= d) ? tot[t - d] : 0;
        __syncthreads();
        tot[t] += x;
        __syncthreads();
    }
    const int excl = tot[t] - v;
    if (t < NB) binStart[t] = excl;
    if (t == NB - 1) binStart[NB] = tot[t];      // == 2*N_EDGES
    if (t == 0) off[N2] = 2 * N_EDGES;           // CSR sentinel
    if (t < NB) {
        int run = excl;
        int* p = counts + t * NBLK;
        for (int i = 0; i < NBLK; i += 4) {
            int4 c = *reinterpret_cast<int4*>(p + i);
            int4 w;
            w.x = run; run += c.x;
            w.y = run; run += c.y;
            w.z = run; run += c.z;
            w.w = run; run += c.w;
            *reinterpret_cast<int4*>(p + i) = w;
        }
    }
}

// ---------------------------------------------------------------------------
// P2: scatter packed records into per-(bin,blk) contiguous sub-ranges.
// rec = (src << 8) | localDst
// ---------------------------------------------------------------------------
__global__ __launch_bounds__(1024) void k_p2_scatter(
    const int* __restrict__ src1, const int* __restrict__ dst1,
    const int* __restrict__ src2, const int* __restrict__ dst2,
    const int* __restrict__ counts, unsigned* __restrict__ binned)
{
    __shared__ int cur[NB];
    const int t = threadIdx.x, b = blockIdx.x;
    if (t < NB) cur[t] = counts[t * NBLK + b];
    __syncthreads();
    const int beg = b * CHUNK;
    const int end = min(beg + CHUNK, 2 * N_EDGES);
    for (int i = beg + t; i < end; i += 1024) {
        int s, idx;
        if (i < N_EDGES) { s = src1[i]; idx = dst1[i]; }
        else             { s = src2[i - N_EDGES]; idx = N_NODES + dst2[i - N_EDGES]; }
        const int bin = idx >> BIN_SHIFT;
        const unsigned rec = ((unsigned)s << BIN_SHIFT) | (unsigned)(idx & (BIN_SZ - 1));
        const int pos = atomicAdd(&cur[bin], 1);
        binned[pos] = rec;
    }
}

// ---------------------------------------------------------------------------
// P3: per-bin CSR build. LDS hist(256) + scan -> off; scatter srcs.
// ---------------------------------------------------------------------------
__global__ __launch_bounds__(1024) void k_p3_csr(
    const unsigned* __restrict__ binned, const int* __restrict__ binStart,
    int* __restrict__ off, int* __restrict__ csr)
{
    __shared__ int hist[BIN_SZ], sc[BIN_SZ], cur[BIN_SZ];
    const int t = threadIdx.x, bin = blockIdx.x;
    const int bs = binStart[bin], be = binStart[bin + 1];
    const int base = bin << BIN_SHIFT;
    const int nloc = min(BIN_SZ, N2 - base);
    if (t < BIN_SZ) hist[t] = 0;
    __syncthreads();
    for (int p = bs + t; p < be; p += 1024)
        atomicAdd(&hist[binned[p] & (BIN_SZ - 1u)], 1);
    __syncthreads();
    int v = 0;
    if (t < BIN_SZ) { v = hist[t]; sc[t] = v; }
    __syncthreads();
    for (int d = 1; d < BIN_SZ; d <<= 1) {
        int x = 0;
        if (t < BIN_SZ && t >= d) x = sc[t - d];
        __syncthreads();
        if (t < BIN_SZ) sc[t] += x;
        __syncthreads();
    }
    if (t < BIN_SZ) {
        const int excl = sc[t] - v;
        cur[t] = bs + excl;
        if (t < nloc) off[base + t] = bs + excl;
    }
    __syncthreads();
    for (int p = bs + t; p < be; p += 1024) {
        const unsigned rec = binned[p];
        const int pos = atomicAdd(&cur[rec & (BIN_SZ - 1u)], 1);
        csr[pos] = (int)(rec >> BIN_SHIFT);
    }
}

// ---------------------------------------------------------------------------
// GEMM 1: y1b = bf16( f @ W1^T )
// ---------------------------------------------------------------------------
__global__ __launch_bounds__(256) void k_gemm1(
    const float* __restrict__ f, const float* __restrict__ W1,
    unsigned short* __restrict__ y1b)
{
    __shared__ float Wt[IN_DIM][HIDDEN + 4];
    __shared__ float S[16][IN_DIM];

    const int t = threadIdx.x;
    for (int i = t; i < HIDDEN * IN_DIM; i += 256) {
        const int o = i >> 7, k = i & 127;
        Wt[k][o] = W1[i];
    }
    const int o4 = (t & 31) * 4;
    const int ln = t >> 5;

    const int ntiles = N_NODES / 16;  // 3125 exact
    for (int tile = blockIdx.x; tile < ntiles; tile += gridDim.x) {
        const int v0 = tile * 16;
        __syncthreads();
        for (int i = t; i < 16 * IN_DIM; i += 256) {
            const int r = i >> 7, k = i & 127;
            S[r][k] = f[(size_t)(v0 + r) * IN_DIM + k];
        }
        __syncthreads();

        float4 acc1 = {0.f, 0.f, 0.f, 0.f};
        float4 acc2 = {0.f, 0.f, 0.f, 0.f};
        const float* s1 = S[ln * 2];
        const float* s2 = S[ln * 2 + 1];
        #pragma unroll 8
        for (int k = 0; k < IN_DIM; k += 4) {
            const float4 sa = *reinterpret_cast<const float4*>(s1 + k);
            const float4 sb = *reinterpret_cast<const float4*>(s2 + k);
            const float4 w0 = *reinterpret_cast<const float4*>(&Wt[k + 0][o4]);
            const float4 w1 = *reinterpret_cast<const float4*>(&Wt[k + 1][o4]);
            const float4 w2 = *reinterpret_cast<const float4*>(&Wt[k + 2][o4]);
            const float4 w3 = *reinterpret_cast<const float4*>(&Wt[k + 3][o4]);
            fma4(acc1, w0, sa.x); fma4(acc1, w1, sa.y); fma4(acc1, w2, sa.z); fma4(acc1, w3, sa.w);
            fma4(acc2, w0, sb.x); fma4(acc2, w1, sb.y); fma4(acc2, w2, sb.z); fma4(acc2, w3, sb.w);
        }
        const int na = v0 + ln * 2, nb = na + 1;
        uint2 pa, pb;
        pa.x = pack_bf2(acc1.x, acc1.y); pa.y = pack_bf2(acc1.z, acc1.w);
        pb.x = pack_bf2(acc2.x, acc2.y); pb.y = pack_bf2(acc2.z, acc2.w);
        *reinterpret_cast<uint2*>(y1b + (size_t)na * HIDDEN + o4) = pa;
        *reinterpret_cast<uint2*>(y1b + (size_t)nb * HIDDEN + o4) = pb;
    }
}

// ---------------------------------------------------------------------------
// GEMM 2: y2b = bf16( x1 @ W2^T )
// ---------------------------------------------------------------------------
__global__ __launch_bounds__(256) void k_gemm2(
    const float* __restrict__ x1, const float* __restrict__ W2,
    unsigned short* __restrict__ y2b)
{
    __shared__ float Wt[IN_DIM][CLASSES + 4];
    __shared__ float S[32][IN_DIM];

    const int t = threadIdx.x;
    for (int i = t; i < CLASSES * IN_DIM; i += 256) {
        const int c = i >> 7, k = i & 127;
        Wt[k][c] = W2[i];
    }
    const int c4 = (t & 15) * 4;
    const int ln = t >> 4;

    const int ntiles = (N_NODES + 31) / 32;  // 1563
    for (int tile = blockIdx.x; tile < ntiles; tile += gridDim.x) {
        const int v0 = tile * 32;
        __syncthreads();
        for (int i = t; i < 32 * IN_DIM; i += 256) {
            const int r = i >> 7, k = i & 127;
            const int node = v0 + r;
            S[r][k] = (node < N_NODES) ? x1[(size_t)node * IN_DIM + k] : 0.f;
        }
        __syncthreads();

        float4 acc1 = {0.f, 0.f, 0.f, 0.f};
        float4 acc2 = {0.f, 0.f, 0.f, 0.f};
        const float* s1 = S[ln * 2];
        const float* s2 = S[ln * 2 + 1];
        #pragma unroll 8
        for (int k = 0; k < IN_DIM; k += 4) {
            const float4 sa = *reinterpret_cast<const float4*>(s1 + k);
            const float4 sb = *reinterpret_cast<const float4*>(s2 + k);
            const float4 w0 = *reinterpret_cast<const float4*>(&Wt[k + 0][c4]);
            const float4 w1 = *reinterpret_cast<const float4*>(&Wt[k + 1][c4]);
            const float4 w2 = *reinterpret_cast<const float4*>(&Wt[k + 2][c4]);
            const float4 w3 = *reinterpret_cast<const float4*>(&Wt[k + 3][c4]);
            fma4(acc1, w0, sa.x); fma4(acc1, w1, sa.y); fma4(acc1, w2, sa.z); fma4(acc1, w3, sa.w);
            fma4(acc2, w0, sb.x); fma4(acc2, w1, sb.y); fma4(acc2, w2, sb.z); fma4(acc2, w3, sb.w);
        }
        const int na = v0 + ln * 2, nb = na + 1;
        uint2 pa, pb;
        pa.x = pack_bf2(acc1.x, acc1.y); pa.y = pack_bf2(acc1.z, acc1.w);
        pb.x = pack_bf2(acc2.x, acc2.y); pb.y = pack_bf2(acc2.z, acc2.w);
        if (na < N_NODES) *reinterpret_cast<uint2*>(y2b + (size_t)na * CLASSES + c4) = pa;
        if (nb < N_NODES) *reinterpret_cast<uint2*>(y2b + (size_t)nb * CLASSES + c4) = pb;
    }
}

// ---------------------------------------------------------------------------
// Pull layer 1 (dim 128): one wave per node. Lane covers 4 dims (uint2 load);
// 32 lanes = full 256 B row; wave processes 2 edges per load instruction
// (half = lane>>5 selects edge parity). Mask-free body, exec-masked odd tail,
// parity partials merged by one shfl_xor(32) per float4.
// ---------------------------------------------------------------------------
__global__ __launch_bounds__(256) void k_pull1(
    const unsigned short* __restrict__ y1b,
    const int* __restrict__ off, const int* __restrict__ csr,
    const float* __restrict__ b1, const float* __restrict__ attn,
    float* __restrict__ x1)
{
    const int lane = threadIdx.x & 63;
    const int v = (blockIdx.x * 256 + threadIdx.x) >> 6;
    if (v >= N_NODES) return;
    const int half = lane >> 5;       // edge parity
    const int l = lane & 31;          // dim group: dims [4l, 4l+4)
    const int c4 = l * 4;

    float4 tot1, tot2;
    #pragma unroll
    for (int g = 0; g < 2; ++g) {
        const int idx = g * N_NODES + v;
        const int beg = off[idx], end_ = off[idx + 1];
        float4 acc = {0.f, 0.f, 0.f, 0.f};
        int j = beg;
        for (; j + 8 <= end_; j += 8) {
            const int s0 = csr[j + half];
            const int s1 = csr[j + 2 + half];
            const int s2 = csr[j + 4 + half];
            const int s3 = csr[j + 6 + half];
            const uint2 u0 = *reinterpret_cast<const uint2*>(y1b + ((s0 << 7) + c4));
            const uint2 u1 = *reinterpret_cast<const uint2*>(y1b + ((s1 << 7) + c4));
            const uint2 u2 = *reinterpret_cast<const uint2*>(y1b + ((s2 << 7) + c4));
            const uint2 u3 = *reinterpret_cast<const uint2*>(y1b + ((s3 << 7) + c4));
            acc4(acc, u0); acc4(acc, u1); acc4(acc, u2); acc4(acc, u3);
        }
        for (; j + 2 <= end_; j += 2) {
            const int s = csr[j + half];
            const uint2 u = *reinterpret_cast<const uint2*>(y1b + ((s << 7) + c4));
            acc4(acc, u);
        }
        if (j < end_ && half == 0) {
            const int s = csr[j];
            const uint2 u = *reinterpret_cast<const uint2*>(y1b + ((s << 7) + c4));
            acc4(acc, u);
        }
        float4 t;
        t.x = acc.x + __shfl_xor(acc.x, 32);
        t.y = acc.y + __shfl_xor(acc.y, 32);
        t.z = acc.z + __shfl_xor(acc.z, 32);
        t.w = acc.w + __shfl_xor(acc.w, 32);
        if (g == 0) tot1 = t; else tot2 = t;
    }

    if (half == 0) {
        const uint2 uy = *reinterpret_cast<const uint2*>(y1b + ((v << 7) + c4));
        const float2 ylo = bf2f2(uy.x), yhi = bf2f2(uy.y);
        const float4 bb = *reinterpret_cast<const float4*>(b1 + c4);
        const float a0 = attn[0], a1 = attn[1];
        float4 r;
        r.x = elu_f(a0 * (ylo.x + tot1.x + bb.x)) + elu_f(a1 * (ylo.x + tot2.x + bb.x));
        r.y = elu_f(a0 * (ylo.y + tot1.y + bb.y)) + elu_f(a1 * (ylo.y + tot2.y + bb.y));
        r.z = elu_f(a0 * (yhi.x + tot1.z + bb.z)) + elu_f(a1 * (yhi.x + tot2.z + bb.z));
        r.w = elu_f(a0 * (yhi.y + tot1.w + bb.w)) + elu_f(a1 * (yhi.y + tot2.w + bb.w));
        *reinterpret_cast<float4*>(x1 + (size_t)v * HIDDEN + c4) = r;
    }
}

// ---------------------------------------------------------------------------
// Pull layer 2 (dim 64): one wave per node. Lane covers 4 dims (uint2);
// 16 lanes = full 128 B row. lane = (g_sel<<5) | (parity<<4) | l.
// Each quarter-wave processes one (graph, parity) stream; merges via
// shfl_xor(16) for parity then shfl_xor(32) for graph exchange.
// ---------------------------------------------------------------------------
__global__ __launch_bounds__(256) void k_pull2(
    const unsigned short* __restrict__ y2b,
    const int* __restrict__ off, const int* __restrict__ csr,
    const float* __restrict__ b2, const float* __restrict__ attn,
    float* __restrict__ out)
{
    const int lane = threadIdx.x & 63;
    const int v = (blockIdx.x * 256 + threadIdx.x) >> 6;
    if (v >= N_NODES) return;
    const int g_sel = lane >> 5;        // graph
    const int par = (lane >> 4) & 1;    // edge parity
    const int l = lane & 15;            // dim group: dims [4l, 4l+4)
    const int c4 = l * 4;

    const int idx = g_sel * N_NODES + v;
    const int beg = off[idx], end_ = off[idx + 1];
    float4 acc = {0.f, 0.f, 0.f, 0.f};
    int j = beg;
    for (; j + 8 <= end_; j += 8) {
        const int s0 = csr[j + par];
        const int s1 = csr[j + 2 + par];
        const int s2 = csr[j + 4 + par];
        const int s3 = csr[j + 6 + par];
        const uint2 u0 = *reinterpret_cast<const uint2*>(y2b + ((s0 << 6) + c4));
        const uint2 u1 = *reinterpret_cast<const uint2*>(y2b + ((s1 << 6) + c4));
        const uint2 u2 = *reinterpret_cast<const uint2*>(y2b + ((s2 << 6) + c4));
        const uint2 u3 = *reinterpret_cast<const uint2*>(y2b + ((s3 << 6) + c4));
        acc4(acc, u0); acc4(acc, u1); acc4(acc, u2); acc4(acc, u3);
    }
    for (; j + 2 <= end_; j += 2) {
        const int s = csr[j + par];
        const uint2 u = *reinterpret_cast<const uint2*>(y2b + ((s << 6) + c4));
        acc4(acc, u);
    }
    if (j < end_ && par == 0) {
        const int s = csr[j];
        const uint2 u = *reinterpret_cast<const uint2*>(y2b + ((s << 6) + c4));
        acc4(acc, u);
    }

    // merge parity within each graph half
    acc.x += __shfl_xor(acc.x, 16);
    acc.y += __shfl_xor(acc.y, 16);
    acc.z += __shfl_xor(acc.z, 16);
    acc.w += __shfl_xor(acc.w, 16);
    // exchange graphs
    float4 other;
    other.x = __shfl_xor(acc.x, 32);
    other.y = __shfl_xor(acc.y, 32);
    other.z = __shfl_xor(acc.z, 32);
    other.w = __shfl_xor(acc.w, 32);
    const float4 t1 = (g_sel == 0) ? acc : other;
    const float4 t2 = (g_sel == 0) ? other : acc;

    if (lane < 16) {
        const uint2 uy = *reinterpret_cast<const uint2*>(y2b + ((v << 6) + c4));
        const float2 ylo = bf2f2(uy.x), yhi = bf2f2(uy.y);
        const float4 bb = *reinterpret_cast<const float4*>(b2 + c4);
        const float a0 = attn[0], a1 = attn[1];
        float4 r;
        r.x = elu_f(a0 * (ylo.x + t1.x + bb.x)) + elu_f(a1 * (ylo.x + t2.x + bb.x));
        r.y = elu_f(a0 * (ylo.y + t1.y + bb.y)) + elu_f(a1 * (ylo.y + t2.y + bb.y));
        r.z = elu_f(a0 * (yhi.x + t1.z + bb.z)) + elu_f(a1 * (yhi.x + t2.z + bb.z));
        r.w = elu_f(a0 * (yhi.y + t1.w + bb.w)) + elu_f(a1 * (yhi.y + t2.w + bb.w));
        *reinterpret_cast<float4*>(out + (size_t)v * CLASSES + c4) = r;
    }
}

extern "C" void kernel_launch(void* const* d_in, const int* in_sizes, int n_in,
                              void* d_out, int out_size, void* d_ws, size_t ws_size,
                              hipStream_t stream)
{
    const float* features = (const float*)d_in[0];
    const float* W1   = (const float*)d_in[1];
    const float* b1   = (const float*)d_in[2];
    const float* W2   = (const float*)d_in[3];
    const float* b2   = (const float*)d_in[4];
    const float* attn = (const float*)d_in[5];
    const int* src1   = (const int*)d_in[6];
    const int* dst1   = (const int*)d_in[7];
    const int* src2   = (const int*)d_in[8];
    const int* dst2   = (const int*)d_in[9];
    float* out = (float*)d_out;

    // workspace layout (segments padded to 16 B multiples)
    float* x1 = (float*)d_ws;                                        // 6.4M f32
    unsigned short* y1b = (unsigned short*)(x1 + (size_t)N_NODES * HIDDEN);   // 6.4M bf16
    unsigned short* y2b = y1b + (size_t)N_NODES * HIDDEN;            // 3.2M bf16
    int* off      = (int*)(y2b + (size_t)N_NODES * CLASSES);         // N2+4 (padded)
    int* binStart = off + (N2 + 4);                                  // NB+1=392
    int* counts   = binStart + 392;                                  // NB*NBLK
    unsigned* binned = (unsigned*)(counts + NB * NBLK);              // 1.6M
    int* csr      = (int*)(binned + 2 * N_EDGES);                    // 1.6M

    // ---- binned CSR build (shared by both layers) ----
    k_p1_count  <<<NBLK, 1024, 0, stream>>>(dst1, dst2, counts);
    k_scan_bins <<<1, 512, 0, stream>>>(counts, binStart, off);
    k_p2_scatter<<<NBLK, 1024, 0, stream>>>(src1, dst1, src2, dst2, counts, binned);
    k_p3_csr    <<<NB, 1024, 0, stream>>>(binned, binStart, off, csr);

    // ---- layer 1 ----
    k_gemm1<<<3125, 256, 0, stream>>>(features, W1, y1b);
    k_pull1<<<12500, 256, 0, stream>>>(y1b, off, csr, b1, attn, x1);

    // ---- layer 2 ----
    k_gemm2<<<1563, 256, 0, stream>>>(x1, W2, y2b);
    k_pull2<<<12500, 256, 0, stream>>>(y2b, off, csr, b2, attn, out);
}

// Round 10
// 281.655 us; speedup vs baseline: 1.2275x; 1.2275x over previous
//
#include <hip/hip_runtime.h>
#include <math.h>

#define N_NODES 50000
#define N_EDGES 800000
#define IN_DIM 128
#define HIDDEN 128
#define CLASSES 64
#define N2 100000      // concatenated node space: graph1 [0,50000), graph2 [50000,100000)

#define BIN_SHIFT 8    // 256 nodes per bin
#define BIN_SZ 256
#define NB 391         // ceil(100000/256)
#define NBLK 256       // edge-partition blocks for P1/P2
#define CHUNK ((2 * N_EDGES + NBLK - 1) / NBLK)

#define NSTRIP 3125    // 50000 / 16 rows per MFMA strip
#define GBLK 391       // ceil(3125 / 8 strips per block)

typedef __attribute__((ext_vector_type(8))) short bf16x8;
typedef __attribute__((ext_vector_type(4))) float f32x4;

union FragU {
    uint4 u4;
    uint2 u2[2];
    bf16x8 f;
};

static __device__ __forceinline__ float elu_f(float x) {
    return x > 0.f ? x : (expf(x) - 1.f);
}

// f32 -> bf16 (RNE) pack of two values into one uint (lo = first)
static __device__ __forceinline__ unsigned pack_bf2(float a, float b) {
    unsigned ua = __float_as_uint(a);
    ua = (ua + 0x7FFFu + ((ua >> 16) & 1u)) >> 16;
    unsigned ub = __float_as_uint(b);
    ub = (ub + 0x7FFFu + ((ub >> 16) & 1u)) >> 16;
    return ua | (ub << 16);
}

static __device__ __forceinline__ unsigned short bf1(float x) {
    unsigned u = __float_as_uint(x);
    u = (u + 0x7FFFu + ((u >> 16) & 1u)) >> 16;
    return (unsigned short)u;
}

// unpack two bf16 (packed in uint) -> float2
static __device__ __forceinline__ float2 bf2f2(unsigned u) {
    float2 r;
    r.x = __uint_as_float(u << 16);
    r.y = __uint_as_float(u & 0xFFFF0000u);
    return r;
}

// accumulate 4 bf16 dims (uint2) into float4
static __device__ __forceinline__ void acc4(float4& a, const uint2 u) {
    const float2 lo = bf2f2(u.x);
    const float2 hi = bf2f2(u.y);
    a.x += lo.x; a.y += lo.y; a.z += hi.x; a.w += hi.y;
}

// ---------------------------------------------------------------------------
// P1: per-block LDS histogram over bins. counts[bin*NBLK + blk] (bin-major).
// ---------------------------------------------------------------------------
__global__ __launch_bounds__(1024) void k_p1_count(
    const int* __restrict__ dst1, const int* __restrict__ dst2,
    int* __restrict__ counts)
{
    __shared__ int hist[NB];
    const int t = threadIdx.x, b = blockIdx.x;
    if (t < NB) hist[t] = 0;
    __syncthreads();
    const int beg = b * CHUNK;
    const int end = min(beg + CHUNK, 2 * N_EDGES);
    for (int i = beg + t; i < end; i += 1024) {
        const int idx = (i < N_EDGES) ? dst1[i] : (N_NODES + dst2[i - N_EDGES]);
        atomicAdd(&hist[idx >> BIN_SHIFT], 1);
    }
    __syncthreads();
    if (t < NB) counts[t * NBLK + b] = hist[t];
}

// ---------------------------------------------------------------------------
// Scan: bin totals, exclusive scan over bins, in-place rewrite counts ->
// per-(bin,blk) start cursors. One 512-thread block.
// ---------------------------------------------------------------------------
__global__ __launch_bounds__(512) void k_scan_bins(
    int* __restrict__ counts, int* __restrict__ binStart, int* __restrict__ off)
{
    __shared__ int tot[512];
    const int t = threadIdx.x;
    int total = 0;
    if (t < NB) {
        const int4* p = reinterpret_cast<const int4*>(counts + t * NBLK);
        #pragma unroll 8
        for (int i = 0; i < NBLK / 4; ++i) {
            const int4 c = p[i];
            total += (c.x + c.y) + (c.z + c.w);
        }
    }
    tot[t] = (t < NB) ? total : 0;
    __syncthreads();
    const int v = tot[t];
    for (int d = 1; d < 512; d <<= 1) {
        const int x = (t >= d) ? tot[t - d] : 0;
        __syncthreads();
        tot[t] += x;
        __syncthreads();
    }
    const int excl = tot[t] - v;
    if (t < NB) binStart[t] = excl;
    if (t == NB - 1) binStart[NB] = tot[t];      // == 2*N_EDGES
    if (t == 0) off[N2] = 2 * N_EDGES;           // CSR sentinel
    if (t < NB) {
        int run = excl;
        int* p = counts + t * NBLK;
        for (int i = 0; i < NBLK; i += 4) {
            int4 c = *reinterpret_cast<int4*>(p + i);
            int4 w;
            w.x = run; run += c.x;
            w.y = run; run += c.y;
            w.z = run; run += c.z;
            w.w = run; run += c.w;
            *reinterpret_cast<int4*>(p + i) = w;
        }
    }
}

// ---------------------------------------------------------------------------
// P2: scatter packed records into per-(bin,blk) contiguous sub-ranges.
// rec = (src << 8) | localDst
// ---------------------------------------------------------------------------
__global__ __launch_bounds__(1024) void k_p2_scatter(
    const int* __restrict__ src1, const int* __restrict__ dst1,
    const int* __restrict__ src2, const int* __restrict__ dst2,
    const int* __restrict__ counts, unsigned* __restrict__ binned)
{
    __shared__ int cur[NB];
    const int t = threadIdx.x, b = blockIdx.x;
    if (t < NB) cur[t] = counts[t * NBLK + b];
    __syncthreads();
    const int beg = b * CHUNK;
    const int end = min(beg + CHUNK, 2 * N_EDGES);
    for (int i = beg + t; i < end; i += 1024) {
        int s, idx;
        if (i < N_EDGES) { s = src1[i]; idx = dst1[i]; }
        else             { s = src2[i - N_EDGES]; idx = N_NODES + dst2[i - N_EDGES]; }
        const int bin = idx >> BIN_SHIFT;
        const unsigned rec = ((unsigned)s << BIN_SHIFT) | (unsigned)(idx & (BIN_SZ - 1));
        const int pos = atomicAdd(&cur[bin], 1);
        binned[pos] = rec;
    }
}

// ---------------------------------------------------------------------------
// P3: per-bin CSR build. LDS hist(256) + scan -> off; scatter srcs.
// ---------------------------------------------------------------------------
__global__ __launch_bounds__(1024) void k_p3_csr(
    const unsigned* __restrict__ binned, const int* __restrict__ binStart,
    int* __restrict__ off, int* __restrict__ csr)
{
    __shared__ int hist[BIN_SZ], sc[BIN_SZ], cur[BIN_SZ];
    const int t = threadIdx.x, bin = blockIdx.x;
    const int bs = binStart[bin], be = binStart[bin + 1];
    const int base = bin << BIN_SHIFT;
    const int nloc = min(BIN_SZ, N2 - base);
    if (t < BIN_SZ) hist[t] = 0;
    __syncthreads();
    for (int p = bs + t; p < be; p += 1024)
        atomicAdd(&hist[binned[p] & (BIN_SZ - 1u)], 1);
    __syncthreads();
    int v = 0;
    if (t < BIN_SZ) { v = hist[t]; sc[t] = v; }
    __syncthreads();
    for (int d = 1; d < BIN_SZ; d <<= 1) {
        int x = 0;
        if (t < BIN_SZ && t >= d) x = sc[t - d];
        __syncthreads();
        if (t < BIN_SZ) sc[t] += x;
        __syncthreads();
    }
    if (t < BIN_SZ) {
        const int excl = sc[t] - v;
        cur[t] = bs + excl;
        if (t < nloc) off[base + t] = bs + excl;
    }
    __syncthreads();
    for (int p = bs + t; p < be; p += 1024) {
        const unsigned rec = binned[p];
        const int pos = atomicAdd(&cur[rec & (BIN_SZ - 1u)], 1);
        csr[pos] = (int)(rec >> BIN_SHIFT);
    }
}

// ---------------------------------------------------------------------------
// GEMM 1 (MFMA): y1b = bf16( f @ W1^T ).  16x16x32 bf16 MFMA.
// Block = 4 waves; wave handles 2 consecutive 16-row strips (32 rows).
// W1 staged in LDS as bf16, rows padded to 140 (280 B = 70 dwords, stride
// ≡ 6 mod 32 -> 2-way bank aliasing = free).
// Frag maps (m89-verified family): A row=lane&15, k=8*(lane>>4)+j;
// B col=lane&15, same k-oct; D col=lane&15, row=4*(lane>>4)+reg.
// ---------------------------------------------------------------------------
__global__ __launch_bounds__(256) void k_gemm1(
    const float* __restrict__ f, const float* __restrict__ W1,
    unsigned short* __restrict__ y1b)
{
    __shared__ unsigned short Wl[HIDDEN][140];
    const int t = threadIdx.x;
    for (int i = t * 4; i < HIDDEN * IN_DIM; i += 1024) {
        const float4 w = *reinterpret_cast<const float4*>(W1 + i);
        const int o = i >> 7, k = i & 127;
        uint2 p;
        p.x = pack_bf2(w.x, w.y);
        p.y = pack_bf2(w.z, w.w);
        *reinterpret_cast<uint2*>(&Wl[o][k]) = p;
    }
    __syncthreads();

    const int wv = t >> 6;
    const int l  = t & 63;
    const int rc = l & 15;     // A-row / B-col / D-col
    const int kq = l >> 4;     // k-oct selector

    const int sid0 = (blockIdx.x * 4 + wv) * 2;
    const int sid1 = sid0 + 1;
    const bool v0 = sid0 < NSTRIP, v1 = sid1 < NSTRIP;
    const int m0 = min(sid0, NSTRIP - 1) * 16;
    const int m1 = min(sid1, NSTRIP - 1) * 16;

    f32x4 acc[2][8];
    #pragma unroll
    for (int st = 0; st < 2; ++st)
        #pragma unroll
        for (int nt = 0; nt < 8; ++nt)
            acc[st][nt] = (f32x4){0.f, 0.f, 0.f, 0.f};

    #pragma unroll
    for (int kc = 0; kc < 4; ++kc) {
        const int kbase = kc * 32 + kq * 8;
        const float* ap0 = f + (size_t)(m0 + rc) * IN_DIM + kbase;
        const float* ap1 = f + (size_t)(m1 + rc) * IN_DIM + kbase;
        const float4 fa0 = *reinterpret_cast<const float4*>(ap0);
        const float4 fa1 = *reinterpret_cast<const float4*>(ap0 + 4);
        const float4 fb0 = *reinterpret_cast<const float4*>(ap1);
        const float4 fb1 = *reinterpret_cast<const float4*>(ap1 + 4);
        FragU A0, A1;
        A0.u4.x = pack_bf2(fa0.x, fa0.y); A0.u4.y = pack_bf2(fa0.z, fa0.w);
        A0.u4.z = pack_bf2(fa1.x, fa1.y); A0.u4.w = pack_bf2(fa1.z, fa1.w);
        A1.u4.x = pack_bf2(fb0.x, fb0.y); A1.u4.y = pack_bf2(fb0.z, fb0.w);
        A1.u4.z = pack_bf2(fb1.x, fb1.y); A1.u4.w = pack_bf2(fb1.z, fb1.w);
        #pragma unroll
        for (int nt = 0; nt < 8; ++nt) {
            const unsigned short* bp = &Wl[nt * 16 + rc][kbase];
            FragU B;
            B.u2[0] = *reinterpret_cast<const uint2*>(bp);
            B.u2[1] = *reinterpret_cast<const uint2*>(bp + 4);
            acc[0][nt] = __builtin_amdgcn_mfma_f32_16x16x32_bf16(A0.f, B.f, acc[0][nt], 0, 0, 0);
            acc[1][nt] = __builtin_amdgcn_mfma_f32_16x16x32_bf16(A1.f, B.f, acc[1][nt], 0, 0, 0);
        }
    }

    #pragma unroll
    for (int st = 0; st < 2; ++st) {
        if (st == 0 ? !v0 : !v1) continue;
        const int mb = (st == 0 ? m0 : m1) + (l >> 4) * 4;
        #pragma unroll
        for (int nt = 0; nt < 8; ++nt) {
            #pragma unroll
            for (int r = 0; r < 4; ++r) {
                y1b[(size_t)(mb + r) * HIDDEN + nt * 16 + rc] = bf1(acc[st][nt][r]);
            }
        }
    }
}

// ---------------------------------------------------------------------------
// GEMM 2 (MFMA): y2b = bf16( x1 @ W2^T ).  N=64 -> 4 n-tiles.
// ---------------------------------------------------------------------------
__global__ __launch_bounds__(256) void k_gemm2(
    const float* __restrict__ x1, const float* __restrict__ W2,
    unsigned short* __restrict__ y2b)
{
    __shared__ unsigned short Wl[CLASSES][140];
    const int t = threadIdx.x;
    for (int i = t * 4; i < CLASSES * IN_DIM; i += 1024) {
        const float4 w = *reinterpret_cast<const float4*>(W2 + i);
        const int o = i >> 7, k = i & 127;
        uint2 p;
        p.x = pack_bf2(w.x, w.y);
        p.y = pack_bf2(w.z, w.w);
        *reinterpret_cast<uint2*>(&Wl[o][k]) = p;
    }
    __syncthreads();

    const int wv = t >> 6;
    const int l  = t & 63;
    const int rc = l & 15;
    const int kq = l >> 4;

    const int sid0 = (blockIdx.x * 4 + wv) * 2;
    const int sid1 = sid0 + 1;
    const bool v0 = sid0 < NSTRIP, v1 = sid1 < NSTRIP;
    const int m0 = min(sid0, NSTRIP - 1) * 16;
    const int m1 = min(sid1, NSTRIP - 1) * 16;

    f32x4 acc[2][4];
    #pragma unroll
    for (int st = 0; st < 2; ++st)
        #pragma unroll
        for (int nt = 0; nt < 4; ++nt)
            acc[st][nt] = (f32x4){0.f, 0.f, 0.f, 0.f};

    #pragma unroll
    for (int kc = 0; kc < 4; ++kc) {
        const int kbase = kc * 32 + kq * 8;
        const float* ap0 = x1 + (size_t)(m0 + rc) * IN_DIM + kbase;
        const float* ap1 = x1 + (size_t)(m1 + rc) * IN_DIM + kbase;
        const float4 fa0 = *reinterpret_cast<const float4*>(ap0);
        const float4 fa1 = *reinterpret_cast<const float4*>(ap0 + 4);
        const float4 fb0 = *reinterpret_cast<const float4*>(ap1);
        const float4 fb1 = *reinterpret_cast<const float4*>(ap1 + 4);
        FragU A0, A1;
        A0.u4.x = pack_bf2(fa0.x, fa0.y); A0.u4.y = pack_bf2(fa0.z, fa0.w);
        A0.u4.z = pack_bf2(fa1.x, fa1.y); A0.u4.w = pack_bf2(fa1.z, fa1.w);
        A1.u4.x = pack_bf2(fb0.x, fb0.y); A1.u4.y = pack_bf2(fb0.z, fb0.w);
        A1.u4.z = pack_bf2(fb1.x, fb1.y); A1.u4.w = pack_bf2(fb1.z, fb1.w);
        #pragma unroll
        for (int nt = 0; nt < 4; ++nt) {
            const unsigned short* bp = &Wl[nt * 16 + rc][kbase];
            FragU B;
            B.u2[0] = *reinterpret_cast<const uint2*>(bp);
            B.u2[1] = *reinterpret_cast<const uint2*>(bp + 4);
            acc[0][nt] = __builtin_amdgcn_mfma_f32_16x16x32_bf16(A0.f, B.f, acc[0][nt], 0, 0, 0);
            acc[1][nt] = __builtin_amdgcn_mfma_f32_16x16x32_bf16(A1.f, B.f, acc[1][nt], 0, 0, 0);
        }
    }

    #pragma unroll
    for (int st = 0; st < 2; ++st) {
        if (st == 0 ? !v0 : !v1) continue;
        const int mb = (st == 0 ? m0 : m1) + (l >> 4) * 4;
        #pragma unroll
        for (int nt = 0; nt < 4; ++nt) {
            #pragma unroll
            for (int r = 0; r < 4; ++r) {
                y2b[(size_t)(mb + r) * CLASSES + nt * 16 + rc] = bf1(acc[st][nt][r]);
            }
        }
    }
}

// ---------------------------------------------------------------------------
// Pull layer 1 (dim 128): one wave per node. Lane covers 4 dims (uint2 load);
// 32 lanes = full 256 B row; wave processes 2 edges per load instruction.
// ---------------------------------------------------------------------------
__global__ __launch_bounds__(256) void k_pull1(
    const unsigned short* __restrict__ y1b,
    const int* __restrict__ off, const int* __restrict__ csr,
    const float* __restrict__ b1, const float* __restrict__ attn,
    float* __restrict__ x1)
{
    const int lane = threadIdx.x & 63;
    const int v = (blockIdx.x * 256 + threadIdx.x) >> 6;
    if (v >= N_NODES) return;
    const int half = lane >> 5;       // edge parity
    const int l = lane & 31;          // dim group: dims [4l, 4l+4)
    const int c4 = l * 4;

    float4 tot1, tot2;
    #pragma unroll
    for (int g = 0; g < 2; ++g) {
        const int idx = g * N_NODES + v;
        const int beg = off[idx], end_ = off[idx + 1];
        float4 acc = {0.f, 0.f, 0.f, 0.f};
        int j = beg;
        for (; j + 8 <= end_; j += 8) {
            const int s0 = csr[j + half];
            const int s1 = csr[j + 2 + half];
            const int s2 = csr[j + 4 + half];
            const int s3 = csr[j + 6 + half];
            const uint2 u0 = *reinterpret_cast<const uint2*>(y1b + ((s0 << 7) + c4));
            const uint2 u1 = *reinterpret_cast<const uint2*>(y1b + ((s1 << 7) + c4));
            const uint2 u2 = *reinterpret_cast<const uint2*>(y1b + ((s2 << 7) + c4));
            const uint2 u3 = *reinterpret_cast<const uint2*>(y1b + ((s3 << 7) + c4));
            acc4(acc, u0); acc4(acc, u1); acc4(acc, u2); acc4(acc, u3);
        }
        for (; j + 2 <= end_; j += 2) {
            const int s = csr[j + half];
            const uint2 u = *reinterpret_cast<const uint2*>(y1b + ((s << 7) + c4));
            acc4(acc, u);
        }
        if (j < end_ && half == 0) {
            const int s = csr[j];
            const uint2 u = *reinterpret_cast<const uint2*>(y1b + ((s << 7) + c4));
            acc4(acc, u);
        }
        float4 tt;
        tt.x = acc.x + __shfl_xor(acc.x, 32);
        tt.y = acc.y + __shfl_xor(acc.y, 32);
        tt.z = acc.z + __shfl_xor(acc.z, 32);
        tt.w = acc.w + __shfl_xor(acc.w, 32);
        if (g == 0) tot1 = tt; else tot2 = tt;
    }

    if (half == 0) {
        const uint2 uy = *reinterpret_cast<const uint2*>(y1b + ((v << 7) + c4));
        const float2 ylo = bf2f2(uy.x), yhi = bf2f2(uy.y);
        const float4 bb = *reinterpret_cast<const float4*>(b1 + c4);
        const float a0 = attn[0], a1 = attn[1];
        float4 r;
        r.x = elu_f(a0 * (ylo.x + tot1.x + bb.x)) + elu_f(a1 * (ylo.x + tot2.x + bb.x));
        r.y = elu_f(a0 * (ylo.y + tot1.y + bb.y)) + elu_f(a1 * (ylo.y + tot2.y + bb.y));
        r.z = elu_f(a0 * (yhi.x + tot1.z + bb.z)) + elu_f(a1 * (yhi.x + tot2.z + bb.z));
        r.w = elu_f(a0 * (yhi.y + tot1.w + bb.w)) + elu_f(a1 * (yhi.y + tot2.w + bb.w));
        *reinterpret_cast<float4*>(x1 + (size_t)v * HIDDEN + c4) = r;
    }
}

// ---------------------------------------------------------------------------
// Pull layer 2 (dim 64): one wave per node; quarter-wave per (graph, parity).
// ---------------------------------------------------------------------------
__global__ __launch_bounds__(256) void k_pull2(
    const unsigned short* __restrict__ y2b,
    const int* __restrict__ off, const int* __restrict__ csr,
    const float* __restrict__ b2, const float* __restrict__ attn,
    float* __restrict__ out)
{
    const int lane = threadIdx.x & 63;
    const int v = (blockIdx.x * 256 + threadIdx.x) >> 6;
    if (v >= N_NODES) return;
    const int g_sel = lane >> 5;        // graph
    const int par = (lane >> 4) & 1;    // edge parity
    const int l = lane & 15;            // dim group: dims [4l, 4l+4)
    const int c4 = l * 4;

    const int idx = g_sel * N_NODES + v;
    const int beg = off[idx], end_ = off[idx + 1];
    float4 acc = {0.f, 0.f, 0.f, 0.f};
    int j = beg;
    for (; j + 8 <= end_; j += 8) {
        const int s0 = csr[j + par];
        const int s1 = csr[j + 2 + par];
        const int s2 = csr[j + 4 + par];
        const int s3 = csr[j + 6 + par];
        const uint2 u0 = *reinterpret_cast<const uint2*>(y2b + ((s0 << 6) + c4));
        const uint2 u1 = *reinterpret_cast<const uint2*>(y2b + ((s1 << 6) + c4));
        const uint2 u2 = *reinterpret_cast<const uint2*>(y2b + ((s2 << 6) + c4));
        const uint2 u3 = *reinterpret_cast<const uint2*>(y2b + ((s3 << 6) + c4));
        acc4(acc, u0); acc4(acc, u1); acc4(acc, u2); acc4(acc, u3);
    }
    for (; j + 2 <= end_; j += 2) {
        const int s = csr[j + par];
        const uint2 u = *reinterpret_cast<const uint2*>(y2b + ((s << 6) + c4));
        acc4(acc, u);
    }
    if (j < end_ && par == 0) {
        const int s = csr[j];
        const uint2 u = *reinterpret_cast<const uint2*>(y2b + ((s << 6) + c4));
        acc4(acc, u);
    }

    // merge parity within each graph half
    acc.x += __shfl_xor(acc.x, 16);
    acc.y += __shfl_xor(acc.y, 16);
    acc.z += __shfl_xor(acc.z, 16);
    acc.w += __shfl_xor(acc.w, 16);
    // exchange graphs
    float4 other;
    other.x = __shfl_xor(acc.x, 32);
    other.y = __shfl_xor(acc.y, 32);
    other.z = __shfl_xor(acc.z, 32);
    other.w = __shfl_xor(acc.w, 32);
    const float4 t1 = (g_sel == 0) ? acc : other;
    const float4 t2 = (g_sel == 0) ? other : acc;

    if (lane < 16) {
        const uint2 uy = *reinterpret_cast<const uint2*>(y2b + ((v << 6) + c4));
        const float2 ylo = bf2f2(uy.x), yhi = bf2f2(uy.y);
        const float4 bb = *reinterpret_cast<const float4*>(b2 + c4);
        const float a0 = attn[0], a1 = attn[1];
        float4 r;
        r.x = elu_f(a0 * (ylo.x + t1.x + bb.x)) + elu_f(a1 * (ylo.x + t2.x + bb.x));
        r.y = elu_f(a0 * (ylo.y + t1.y + bb.y)) + elu_f(a1 * (ylo.y + t2.y + bb.y));
        r.z = elu_f(a0 * (yhi.x + t1.z + bb.z)) + elu_f(a1 * (yhi.x + t2.z + bb.z));
        r.w = elu_f(a0 * (yhi.y + t1.w + bb.w)) + elu_f(a1 * (yhi.y + t2.w + bb.w));
        *reinterpret_cast<float4*>(out + (size_t)v * CLASSES + c4) = r;
    }
}

extern "C" void kernel_launch(void* const* d_in, const int* in_sizes, int n_in,
                              void* d_out, int out_size, void* d_ws, size_t ws_size,
                              hipStream_t stream)
{
    const float* features = (const float*)d_in[0];
    const float* W1   = (const float*)d_in[1];
    const float* b1   = (const float*)d_in[2];
    const float* W2   = (const float*)d_in[3];
    const float* b2   = (const float*)d_in[4];
    const float* attn = (const float*)d_in[5];
    const int* src1   = (const int*)d_in[6];
    const int* dst1   = (const int*)d_in[7];
    const int* src2   = (const int*)d_in[8];
    const int* dst2   = (const int*)d_in[9];
    float* out = (float*)d_out;

    // workspace layout (segments padded to 16 B multiples)
    float* x1 = (float*)d_ws;                                        // 6.4M f32
    unsigned short* y1b = (unsigned short*)(x1 + (size_t)N_NODES * HIDDEN);   // 6.4M bf16
    unsigned short* y2b = y1b + (size_t)N_NODES * HIDDEN;            // 3.2M bf16
    int* off      = (int*)(y2b + (size_t)N_NODES * CLASSES);         // N2+4 (padded)
    int* binStart = off + (N2 + 4);                                  // NB+1=392
    int* counts   = binStart + 392;                                  // NB*NBLK
    unsigned* binned = (unsigned*)(counts + NB * NBLK);              // 1.6M
    int* csr      = (int*)(binned + 2 * N_EDGES);                    // 1.6M

    // ---- binned CSR build (shared by both layers) ----
    k_p1_count  <<<NBLK, 1024, 0, stream>>>(dst1, dst2, counts);
    k_scan_bins <<<1, 512, 0, stream>>>(counts, binStart, off);
    k_p2_scatter<<<NBLK, 1024, 0, stream>>>(src1, dst1, src2, dst2, counts, binned);
    k_p3_csr    <<<NB, 1024, 0, stream>>>(binned, binStart, off, csr);

    // ---- layer 1 ----
    k_gemm1<<<GBLK, 256, 0, stream>>>(features, W1, y1b);
    k_pull1<<<12500, 256, 0, stream>>>(y1b, off, csr, b1, attn, x1);

    // ---- layer 2 ----
    k_gemm2<<<GBLK, 256, 0, stream>>>(x1, W2, y2b);
    k_pull2<<<12500, 256, 0, stream>>>(y2b, off, csr, b2, attn, out);
}